// Round 11
// baseline (212.740 us; speedup 1.0000x reference)
//
#include <hip/hip_runtime.h>
#include <hip/hip_bf16.h>

namespace {

constexpr int kB = 8, kT = 64, kE = 4, kD = 256, kH = 1024;
constexpr int kNC = 4;            // h-chunks per (t,e): grid = 256*4 = 1024
constexpr int kHc = kH / kNC;     // 256 h per chunk; each wave owns 64 of them

typedef float floatx4 __attribute__((ext_vector_type(4)));

__device__ __forceinline__ float gelu_exact(float v) {
  return 0.5f * v * (1.0f + erff(v * 0.70710678118654752f));
}

__device__ __forceinline__ float4 ntload4(const float4* p) {
  const floatx4 v = __builtin_nontemporal_load(reinterpret_cast<const floatx4*>(p));
  return make_float4(v.x, v.y, v.z, v.w);
}

// grid 1024 = (te, chunk c); 4 waves/block; wave w privately owns h-sub
// [256c + 64w, +64) for BOTH phases. One barrier total (after x staging).
__global__ __launch_bounds__(256, 4)
void moe_ffn_kernel(const float* __restrict__ x,
                    const float* __restrict__ fc1,
                    const float* __restrict__ b1,
                    const float* __restrict__ fc2,
                    const float* __restrict__ b2,
                    const float* __restrict__ Wr,
                    const float* __restrict__ br,
                    float* __restrict__ out) {
  __shared__ float xs[kB][kD];   // 8 KB

  const int tid  = threadIdx.x;
  const int bid  = blockIdx.x;    // te * kNC + c
  const int te   = bid >> 2;
  const int c    = bid & 3;
  const int t    = te >> 2;
  const int wave = tid >> 6, lane = tid & 63;
  const int hbase = c * kHc + wave * 64;   // wave-private 64-h sub-chunk

  // ---- stage x[b, t, :] into LDS as float4 ----
  {
    const float4* __restrict__ xsrc = reinterpret_cast<const float4*>(x);
    float4* xdst = reinterpret_cast<float4*>(&xs[0][0]);
#pragma unroll
    for (int i = 0; i < 2; ++i) {
      const int f = i * 256 + tid;          // 0..511 float4s
      const int b = f >> 6, d4 = f & 63;
      xdst[f] = xsrc[(size_t)(b * kT + t) * (kD / 4) + d4];
    }
  }
  __syncthreads();   // the ONLY block-wide barrier

  // ---- router gates, per wave (every lane ends with all 8 gates) ----
  float gates[kB];
  {
    const float* __restrict__ wr = Wr + (size_t)te * kD;
    const float w0 = wr[lane], w1 = wr[lane + 64], w2 = wr[lane + 128], w3 = wr[lane + 192];
    const float brv = br[te];
#pragma unroll
    for (int b = 0; b < kB; ++b) {
      float p = xs[b][lane] * w0 + xs[b][lane + 64] * w1 +
                xs[b][lane + 128] * w2 + xs[b][lane + 192] * w3;
#pragma unroll
      for (int off = 32; off; off >>= 1) p += __shfl_xor(p, off);
      const float g = p + brv;
      gates[b] = g > 0.0f ? g : 0.0f;
    }
  }

  // ---- phase 1: wave computes hid for its 64 h over all 256 d ----
  // lane = dslice*16 + hq16: lane group dslice covers d in [64*dslice, +64),
  // 16 lanes cover the 16 h-float4 columns. Cross-slice combine via shfl_xor.
  const int hq16   = lane & 15;
  const int dslice = lane >> 4;
  float4 hid[kB];
  {
    float4 a[kB];
#pragma unroll
    for (int b = 0; b < kB; ++b) a[b] = make_float4(0.f, 0.f, 0.f, 0.f);
    const float4* __restrict__ wp =
        reinterpret_cast<const float4*>(fc1 + (size_t)te * (kD * kH));  // [d][kH/4]
    const int hcol = (hbase >> 2) + hq16;
#pragma unroll 2
    for (int ig = 0; ig < 16; ++ig) {
      // stagger per d-slice so xs broadcast groups hit different banks
      const int ige = (ig + dslice * 4) & 15;
      const int d   = dslice * 64 + ige * 4;
      const float4 wv0 = ntload4(wp + (size_t)(d + 0) * (kH / 4) + hcol);
      const float4 wv1 = ntload4(wp + (size_t)(d + 1) * (kH / 4) + hcol);
      const float4 wv2 = ntload4(wp + (size_t)(d + 2) * (kH / 4) + hcol);
      const float4 wv3 = ntload4(wp + (size_t)(d + 3) * (kH / 4) + hcol);
#pragma unroll
      for (int b = 0; b < kB; ++b) {
        const float4 xv = *reinterpret_cast<const float4*>(&xs[b][d]);
        a[b].x = fmaf(xv.x, wv0.x, a[b].x);
        a[b].y = fmaf(xv.x, wv0.y, a[b].y);
        a[b].z = fmaf(xv.x, wv0.z, a[b].z);
        a[b].w = fmaf(xv.x, wv0.w, a[b].w);
        a[b].x = fmaf(xv.y, wv1.x, a[b].x);
        a[b].y = fmaf(xv.y, wv1.y, a[b].y);
        a[b].z = fmaf(xv.y, wv1.z, a[b].z);
        a[b].w = fmaf(xv.y, wv1.w, a[b].w);
        a[b].x = fmaf(xv.z, wv2.x, a[b].x);
        a[b].y = fmaf(xv.z, wv2.y, a[b].y);
        a[b].z = fmaf(xv.z, wv2.z, a[b].z);
        a[b].w = fmaf(xv.z, wv2.w, a[b].w);
        a[b].x = fmaf(xv.w, wv3.x, a[b].x);
        a[b].y = fmaf(xv.w, wv3.y, a[b].y);
        a[b].z = fmaf(xv.w, wv3.z, a[b].z);
        a[b].w = fmaf(xv.w, wv3.w, a[b].w);
      }
    }
    // combine the 4 d-slices (butterfly over lane bits 4,5); all lanes get sum
#pragma unroll
    for (int b = 0; b < kB; ++b) {
      a[b].x += __shfl_xor(a[b].x, 16); a[b].y += __shfl_xor(a[b].y, 16);
      a[b].z += __shfl_xor(a[b].z, 16); a[b].w += __shfl_xor(a[b].w, 16);
      a[b].x += __shfl_xor(a[b].x, 32); a[b].y += __shfl_xor(a[b].y, 32);
      a[b].z += __shfl_xor(a[b].z, 32); a[b].w += __shfl_xor(a[b].w, 32);
    }
    const float4 bias =
        *reinterpret_cast<const float4*>(&b1[(size_t)te * kH + hbase + 4 * hq16]);
#pragma unroll
    for (int b = 0; b < kB; ++b) {
      hid[b].x = gelu_exact(a[b].x + bias.x);
      hid[b].y = gelu_exact(a[b].y + bias.y);
      hid[b].z = gelu_exact(a[b].z + bias.z);
      hid[b].w = gelu_exact(a[b].w + bias.w);
    }
  }

  // ---- phase 2: wave streams its 64 fc2 rows (64 KB sequential, NT) ----
  // lane owns d-quad 4*lane; hid[b][row] broadcast from lane row>>2.
  float4 acc2[kB];
#pragma unroll
  for (int b = 0; b < kB; ++b) acc2[b] = make_float4(0.f, 0.f, 0.f, 0.f);
  {
    const float4* __restrict__ wp2 =
        reinterpret_cast<const float4*>(fc2 + (size_t)te * (kH * kD)) + lane;  // [h][kD/4]
#pragma unroll 2
    for (int hg = 0; hg < 16; ++hg) {
      const int hrow = hbase + hg * 4;
      const float4 wv0 = ntload4(wp2 + (size_t)(hrow + 0) * (kD / 4));
      const float4 wv1 = ntload4(wp2 + (size_t)(hrow + 1) * (kD / 4));
      const float4 wv2 = ntload4(wp2 + (size_t)(hrow + 2) * (kD / 4));
      const float4 wv3 = ntload4(wp2 + (size_t)(hrow + 3) * (kD / 4));
      const int src = hg << 2;  // owning lanes: src, src+1, src+2, src+3? no:
      // rows hrow..hrow+3 live in lane (hrow-hbase)/4 = hg, components 0..3.
#pragma unroll
      for (int b = 0; b < kB; ++b) {
        const float hx = __shfl(hid[b].x, hg);
        const float hy = __shfl(hid[b].y, hg);
        const float hz = __shfl(hid[b].z, hg);
        const float hw = __shfl(hid[b].w, hg);
        acc2[b].x = fmaf(hx, wv0.x, acc2[b].x);
        acc2[b].y = fmaf(hx, wv0.y, acc2[b].y);
        acc2[b].z = fmaf(hx, wv0.z, acc2[b].z);
        acc2[b].w = fmaf(hx, wv0.w, acc2[b].w);
        acc2[b].x = fmaf(hy, wv1.x, acc2[b].x);
        acc2[b].y = fmaf(hy, wv1.y, acc2[b].y);
        acc2[b].z = fmaf(hy, wv1.z, acc2[b].z);
        acc2[b].w = fmaf(hy, wv1.w, acc2[b].w);
        acc2[b].x = fmaf(hz, wv2.x, acc2[b].x);
        acc2[b].y = fmaf(hz, wv2.y, acc2[b].y);
        acc2[b].z = fmaf(hz, wv2.z, acc2[b].z);
        acc2[b].w = fmaf(hz, wv2.w, acc2[b].w);
        acc2[b].x = fmaf(hw, wv3.x, acc2[b].x);
        acc2[b].y = fmaf(hw, wv3.y, acc2[b].y);
        acc2[b].z = fmaf(hw, wv3.z, acc2[b].z);
        acc2[b].w = fmaf(hw, wv3.w, acc2[b].w);
      }
      (void)src;
    }
  }

  // ---- epilogue: each wave atomically adds its partial (d-quad per lane) ----
  {
    const int d0 = 4 * lane;
    float4 b2v = make_float4(0.f, 0.f, 0.f, 0.f);
    if (c == 0 && wave == 0)
      b2v = *reinterpret_cast<const float4*>(&b2[(size_t)te * kD + d0]);
#pragma unroll
    for (int b = 0; b < kB; ++b) {
      const float g = gates[b];
      float* o = &out[((size_t)b * kT + t) * kD + d0];
      atomicAdd(o + 0, g * (acc2[b].x + b2v.x));
      atomicAdd(o + 1, g * (acc2[b].y + b2v.y));
      atomicAdd(o + 2, g * (acc2[b].z + b2v.z));
      atomicAdd(o + 3, g * (acc2[b].w + b2v.w));
    }
    if (c == 0 && tid == 0) {
      float gs = 0.f;
#pragma unroll
      for (int b = 0; b < kB; ++b) gs += gates[b];
      atomicAdd(&out[(size_t)kB * kT * kD], 0.01f * gs * (1.0f / (kB * kT)));
    }
  }
}

}  // namespace

extern "C" void kernel_launch(void* const* d_in, const int* in_sizes, int n_in,
                              void* d_out, int out_size, void* d_ws, size_t ws_size,
                              hipStream_t stream) {
  const float* x   = (const float*)d_in[0];
  const float* fc1 = (const float*)d_in[1];
  const float* b1  = (const float*)d_in[2];
  const float* fc2 = (const float*)d_in[3];
  const float* b2  = (const float*)d_in[4];
  const float* Wr  = (const float*)d_in[5];
  const float* br  = (const float*)d_in[6];
  float* out = (float*)d_out;

  // Zero the accumulation target every call (graph replays must be
  // deterministic; harness does not re-poison between replays).
  (void)hipMemsetAsync(d_out, 0, (size_t)out_size * sizeof(float), stream);

  moe_ffn_kernel<<<dim3(kT * kE * kNC), dim3(256), 0, stream>>>(
      x, fc1, b1, fc2, b2, Wr, br, out);
}

// Round 12
// 148.813 us; speedup vs baseline: 1.4296x; 1.4296x over previous
//
#include <hip/hip_runtime.h>
#include <hip/hip_bf16.h>

namespace {

constexpr int kB = 8, kT = 64, kE = 4, kD = 256, kH = 1024;
constexpr int kNC = 8;            // h-chunks per (t,e) -> grid 2048, 8 blocks/CU
constexpr int kHc = kH / kNC;     // 128 h = 32 float4 quads per chunk

typedef float floatx4 __attribute__((ext_vector_type(4)));

__device__ __forceinline__ float gelu_exact(float v) {
  return 0.5f * v * (1.0f + erff(v * 0.70710678118654752f));
}

__device__ __forceinline__ float4 ntload4(const float4* p) {
  const floatx4 v = __builtin_nontemporal_load(reinterpret_cast<const floatx4*>(p));
  return make_float4(v.x, v.y, v.z, v.w);
}

__global__ __launch_bounds__(256, 8)
void moe_ffn_kernel(const float* __restrict__ x,
                    const float* __restrict__ fc1,
                    const float* __restrict__ b1,
                    const float* __restrict__ fc2,
                    const float* __restrict__ b2,
                    const float* __restrict__ Wr,
                    const float* __restrict__ br,
                    float* __restrict__ out) {
  // xs is reused as 'red' in phase 2 (dead after phase 1) to fit 8 blocks/CU.
  __shared__ float xs[kB][kD];     // 8 KB (phase 1: x; phase 2: output partials)
  __shared__ float hid[kB][kHc];   // 4 KB
  __shared__ float gates_s[kB];

  const int tid  = threadIdx.x;
  const int bid  = blockIdx.x;     // te * kNC + c
  const int te   = bid >> 3;
  const int c    = bid & 7;
  const int t    = te >> 2;
  const int wave = tid >> 6, lane = tid & 63;

  // ---- stage x[b, t, :] into LDS as float4 ----
  {
    const float4* __restrict__ xsrc = reinterpret_cast<const float4*>(x);
    float4* xdst = reinterpret_cast<float4*>(&xs[0][0]);
#pragma unroll
    for (int i = 0; i < 2; ++i) {
      const int f = i * 256 + tid;          // 0..511 float4s
      const int b = f >> 6, d4 = f & 63;
      xdst[f] = xsrc[(size_t)(b * kT + t) * (kD / 4) + d4];
    }
  }
  __syncthreads();

  // ---- router gates: wave w computes b = 2w, 2w+1 ----
  {
    const float* __restrict__ wr = Wr + (size_t)te * kD;
    const float w0 = wr[lane], w1 = wr[lane + 64], w2 = wr[lane + 128], w3 = wr[lane + 192];
#pragma unroll
    for (int bb = 0; bb < 2; ++bb) {
      const int b = wave * 2 + bb;
      float p = xs[b][lane] * w0 + xs[b][lane + 64] * w1 +
                xs[b][lane + 128] * w2 + xs[b][lane + 192] * w3;
#pragma unroll
      for (int off = 32; off; off >>= 1) p += __shfl_xor(p, off);
      if (lane == 0) {
        const float g = p + br[te];
        gates_s[b] = g > 0.0f ? g : 0.0f;
      }
    }
  }

  // ---- phase 1: wave owns d-quarter [64*wave,+64); lane = (row-parity r, quad q) ----
  // Load instr covers 2 rows x 32 quads = 2 x 512 B contiguous segments (NT dwordx4).
  const int q = lane & 31, r = lane >> 5;
  const int hq = c * 32 + q;               // global float4 column in fc1 row
  float4 a[kB];
#pragma unroll
  for (int b = 0; b < kB; ++b) a[b] = make_float4(0.f, 0.f, 0.f, 0.f);
  {
    const float4* __restrict__ wp =
        reinterpret_cast<const float4*>(fc1 + (size_t)te * (kD * kH));  // [d][kH/4]
    const int d0 = wave * 64;
#pragma unroll 4
    for (int dg = 0; dg < 16; ++dg) {
      const int dbase = d0 + dg * 4;
      const int row0 = dbase + r;          // rows dbase / dbase+1
      const int row1 = dbase + 2 + r;      // rows dbase+2 / dbase+3
      const float4 wv0 = ntload4(wp + (size_t)row0 * (kH / 4) + hq);
      const float4 wv1 = ntload4(wp + (size_t)row1 * (kH / 4) + hq);
#pragma unroll
      for (int b = 0; b < kB; ++b) {
        const float x0 = xs[b][row0];
        const float x1 = xs[b][row1];
        a[b].x = fmaf(x0, wv0.x, a[b].x);
        a[b].y = fmaf(x0, wv0.y, a[b].y);
        a[b].z = fmaf(x0, wv0.z, a[b].z);
        a[b].w = fmaf(x0, wv0.w, a[b].w);
        a[b].x = fmaf(x1, wv1.x, a[b].x);
        a[b].y = fmaf(x1, wv1.y, a[b].y);
        a[b].z = fmaf(x1, wv1.z, a[b].z);
        a[b].w = fmaf(x1, wv1.w, a[b].w);
      }
    }
    // combine row-parity halves (lane <-> lane^32 hold the same quad)
#pragma unroll
    for (int b = 0; b < kB; ++b) {
      a[b].x += __shfl_xor(a[b].x, 32);
      a[b].y += __shfl_xor(a[b].y, 32);
      a[b].z += __shfl_xor(a[b].z, 32);
      a[b].w += __shfl_xor(a[b].w, 32);
    }
  }
  // rotation combine across the 4 d-quarter waves into hid (quads)
  {
    float4* hidq = reinterpret_cast<float4*>(&hid[0][0]);   // [b*32 + q]
#pragma unroll
    for (int g = 0; g < 4; ++g) {
      if (wave == g && lane < 32) {
#pragma unroll
        for (int b = 0; b < kB; ++b) {
          const int idx = b * 32 + q;
          if (g == 0) {
            hidq[idx] = a[b];
          } else {
            float4 v = hidq[idx];
            v.x += a[b].x; v.y += a[b].y; v.z += a[b].z; v.w += a[b].w;
            hidq[idx] = v;
          }
        }
      }
      __syncthreads();
    }
    // bias + gelu: thread owns one hid quad
    const int bb = tid >> 5, q2 = tid & 31;
    float4 v = hidq[bb * 32 + q2];
    const float4 bias =
        reinterpret_cast<const float4*>(b1 + (size_t)te * kH + c * kHc)[q2];
    v.x = gelu_exact(v.x + bias.x);
    v.y = gelu_exact(v.y + bias.y);
    v.z = gelu_exact(v.z + bias.z);
    v.w = gelu_exact(v.w + bias.w);
    hidq[bb * 32 + q2] = v;
  }
  __syncthreads();

  // ---- phase 2: wave owns 32 sequential fc2 rows; lane owns quad 'lane' (1 KB/row) ----
  float4 acc2[kB];
#pragma unroll
  for (int b = 0; b < kB; ++b) acc2[b] = make_float4(0.f, 0.f, 0.f, 0.f);
  {
    const float4* __restrict__ wp2 =
        reinterpret_cast<const float4*>(fc2 + (size_t)te * (kH * kD)) + lane;  // [h][kD/4]
    const int hb = wave * 32;
#pragma unroll 2
    for (int hg = 0; hg < 8; ++hg) {
      const int hl = hb + hg * 4;          // local h rows hl..hl+3
      const int hrow = c * kHc + hl;       // global fc2 row
      const float4 wv0 = ntload4(wp2 + (size_t)(hrow + 0) * (kD / 4));
      const float4 wv1 = ntload4(wp2 + (size_t)(hrow + 1) * (kD / 4));
      const float4 wv2 = ntload4(wp2 + (size_t)(hrow + 2) * (kD / 4));
      const float4 wv3 = ntload4(wp2 + (size_t)(hrow + 3) * (kD / 4));
#pragma unroll
      for (int b = 0; b < kB; ++b) {
        const float4 hv = *reinterpret_cast<const float4*>(&hid[b][hl]);  // b128 bcast
        acc2[b].x = fmaf(hv.x, wv0.x, acc2[b].x);
        acc2[b].y = fmaf(hv.x, wv0.y, acc2[b].y);
        acc2[b].z = fmaf(hv.x, wv0.z, acc2[b].z);
        acc2[b].w = fmaf(hv.x, wv0.w, acc2[b].w);
        acc2[b].x = fmaf(hv.y, wv1.x, acc2[b].x);
        acc2[b].y = fmaf(hv.y, wv1.y, acc2[b].y);
        acc2[b].z = fmaf(hv.y, wv1.z, acc2[b].z);
        acc2[b].w = fmaf(hv.y, wv1.w, acc2[b].w);
        acc2[b].x = fmaf(hv.z, wv2.x, acc2[b].x);
        acc2[b].y = fmaf(hv.z, wv2.y, acc2[b].y);
        acc2[b].z = fmaf(hv.z, wv2.z, acc2[b].z);
        acc2[b].w = fmaf(hv.z, wv2.w, acc2[b].w);
        acc2[b].x = fmaf(hv.w, wv3.x, acc2[b].x);
        acc2[b].y = fmaf(hv.w, wv3.y, acc2[b].y);
        acc2[b].z = fmaf(hv.w, wv3.z, acc2[b].z);
        acc2[b].w = fmaf(hv.w, wv3.w, acc2[b].w);
      }
    }
  }
  // rotation combine into red (aliases xs; xs is dead after phase 1)
  {
    float4* redq = reinterpret_cast<float4*>(&xs[0][0]);   // [b*64 + lane]
#pragma unroll
    for (int g = 0; g < 4; ++g) {
      if (wave == g) {
#pragma unroll
        for (int b = 0; b < kB; ++b) {
          const int idx = b * 64 + lane;
          if (g == 0) {
            redq[idx] = acc2[b];
          } else {
            float4 v = redq[idx];
            v.x += acc2[b].x; v.y += acc2[b].y; v.z += acc2[b].z; v.w += acc2[b].w;
            redq[idx] = v;
          }
        }
      }
      __syncthreads();
    }
  }

  // ---- epilogue: thread owns d = tid; coalesced scalar atomics (R8 pattern) ----
  {
    const float* red = &xs[0][0];
    const float b2v = (c == 0) ? b2[(size_t)te * kD + tid] : 0.f;
#pragma unroll
    for (int b = 0; b < kB; ++b)
      atomicAdd(&out[((size_t)b * kT + t) * kD + tid],
                gates_s[b] * (red[b * kD + tid] + b2v));

    if (c == 0 && tid == 0) {
      float gs = 0.f;
#pragma unroll
      for (int b = 0; b < kB; ++b) gs += gates_s[b];
      atomicAdd(&out[(size_t)kB * kT * kD], 0.01f * gs * (1.0f / (kB * kT)));
    }
  }
}

}  // namespace

extern "C" void kernel_launch(void* const* d_in, const int* in_sizes, int n_in,
                              void* d_out, int out_size, void* d_ws, size_t ws_size,
                              hipStream_t stream) {
  const float* x   = (const float*)d_in[0];
  const float* fc1 = (const float*)d_in[1];
  const float* b1  = (const float*)d_in[2];
  const float* fc2 = (const float*)d_in[3];
  const float* b2  = (const float*)d_in[4];
  const float* Wr  = (const float*)d_in[5];
  const float* br  = (const float*)d_in[6];
  float* out = (float*)d_out;

  // Zero the accumulation target every call (graph replays must be
  // deterministic; harness does not re-poison between replays).
  (void)hipMemsetAsync(d_out, 0, (size_t)out_size * sizeof(float), stream);

  moe_ffn_kernel<<<dim3(kT * kE * kNC), dim3(256), 0, stream>>>(
      x, fc1, b1, fc2, b2, Wr, br, out);
}

// Round 13
// 96.048 us; speedup vs baseline: 2.2149x; 1.5494x over previous
//
#include <hip/hip_runtime.h>
#include <hip/hip_bf16.h>

namespace {

constexpr int kB = 8, kT = 64, kE = 4, kD = 256, kH = 1024;
constexpr int kNC = 4;            // H-chunks per (t,e) -> grid 1024
constexpr int kHc = kH / kNC;     // 256

typedef float floatx4 __attribute__((ext_vector_type(4)));

__device__ __forceinline__ float gelu_exact(float v) {
  return 0.5f * v * (1.0f + erff(v * 0.70710678118654752f));
}

__device__ __forceinline__ float4 ntload4(const float4* p) {
  const floatx4 v = __builtin_nontemporal_load(reinterpret_cast<const floatx4*>(p));
  return make_float4(v.x, v.y, v.z, v.w);
}

__global__ __launch_bounds__(256, 4)
void moe_ffn_kernel(const float* __restrict__ x,
                    const float* __restrict__ fc1,
                    const float* __restrict__ b1,
                    const float* __restrict__ fc2,
                    const float* __restrict__ b2,
                    const float* __restrict__ Wr,
                    const float* __restrict__ br,
                    float* __restrict__ out) {
  __shared__ float xs[kB][kD];      // 8 KB
  __shared__ float hid[kB][kHc];    // 8 KB
  __shared__ float red[kB][kD];     // 8 KB
  __shared__ float gates_s[kB];

  const int tid  = threadIdx.x;
  const int bid  = blockIdx.x;      // te * kNC + c
  const int te   = bid >> 2;
  const int c    = bid & 3;
  const int t    = te >> 2;
  const int h0   = c * kHc;
  const int wave = tid >> 6, lane = tid & 63;

  // ---- stage x[b, t, :] into LDS as float4 (cached loads) ----
  {
    const float4* __restrict__ xsrc = reinterpret_cast<const float4*>(x);
    float4* xdst = reinterpret_cast<float4*>(&xs[0][0]);
#pragma unroll
    for (int i = 0; i < 2; ++i) {
      const int f = i * 256 + tid;            // 0..511 float4s
      const int b = f >> 6, d4 = f & 63;
      xdst[f] = xsrc[(size_t)(b * kT + t) * (kD / 4) + d4];
    }
  }
  __syncthreads();

  // ---- router gates: wave w computes b = 2w, 2w+1 ----
  {
    const float* __restrict__ wr = Wr + (size_t)te * kD;
    const float w0 = wr[lane], w1 = wr[lane + 64], w2 = wr[lane + 128], w3 = wr[lane + 192];
#pragma unroll
    for (int bb = 0; bb < 2; ++bb) {
      const int b = wave * 2 + bb;
      float p = xs[b][lane] * w0 + xs[b][lane + 64] * w1 +
                xs[b][lane + 128] * w2 + xs[b][lane + 192] * w3;
#pragma unroll
      for (int off = 32; off; off >>= 1) p += __shfl_xor(p, off);
      if (lane == 0) {
        const float g = p + br[te];
        gates_s[b] = g > 0.0f ? g : 0.0f;
      }
    }
  }

  // ---- phase 1: wave owns d-quarter [64*wave, +64); lane owns h = h0+4*lane..+3 ----
  // fc1 loads: non-temporal dwordx4, 1 KB contiguous per wave-instr.
  float4 acc[kB];
#pragma unroll
  for (int b = 0; b < kB; ++b) acc[b] = make_float4(0.f, 0.f, 0.f, 0.f);
  {
    const float4* __restrict__ wp =
        reinterpret_cast<const float4*>(fc1 + (size_t)te * (kD * kH));  // [d][kH/4]
    const int hq = (h0 >> 2) + lane;
    const int d0 = wave * 64;
    for (int dg = 0; dg < 16; ++dg) {
      const int d = d0 + dg * 4;
      const float4 wv0 = ntload4(wp + (size_t)(d + 0) * (kH / 4) + hq);
      const float4 wv1 = ntload4(wp + (size_t)(d + 1) * (kH / 4) + hq);
      const float4 wv2 = ntload4(wp + (size_t)(d + 2) * (kH / 4) + hq);
      const float4 wv3 = ntload4(wp + (size_t)(d + 3) * (kH / 4) + hq);
#pragma unroll
      for (int b = 0; b < kB; ++b) {
        const float4 xv = *reinterpret_cast<const float4*>(&xs[b][d]);
        acc[b].x = fmaf(xv.x, wv0.x, acc[b].x);
        acc[b].y = fmaf(xv.x, wv0.y, acc[b].y);
        acc[b].z = fmaf(xv.x, wv0.z, acc[b].z);
        acc[b].w = fmaf(xv.x, wv0.w, acc[b].w);
        acc[b].x = fmaf(xv.y, wv1.x, acc[b].x);
        acc[b].y = fmaf(xv.y, wv1.y, acc[b].y);
        acc[b].z = fmaf(xv.y, wv1.z, acc[b].z);
        acc[b].w = fmaf(xv.y, wv1.w, acc[b].w);
        acc[b].x = fmaf(xv.z, wv2.x, acc[b].x);
        acc[b].y = fmaf(xv.z, wv2.y, acc[b].y);
        acc[b].z = fmaf(xv.z, wv2.z, acc[b].z);
        acc[b].w = fmaf(xv.z, wv2.w, acc[b].w);
        acc[b].x = fmaf(xv.w, wv3.x, acc[b].x);
        acc[b].y = fmaf(xv.w, wv3.y, acc[b].y);
        acc[b].z = fmaf(xv.w, wv3.z, acc[b].z);
        acc[b].w = fmaf(xv.w, wv3.w, acc[b].w);
      }
    }
  }
  // cross-wave combine into hid by rotation (sequential b128, conflict-free)
#pragma unroll
  for (int g = 0; g < 4; ++g) {
    if (wave == g) {
#pragma unroll
      for (int b = 0; b < kB; ++b) {
        float4* hp = reinterpret_cast<float4*>(&hid[b][0]) + lane;
        if (g == 0) {
          *hp = acc[b];
        } else {
          float4 v = *hp;
          v.x += acc[b].x; v.y += acc[b].y; v.z += acc[b].z; v.w += acc[b].w;
          *hp = v;
        }
      }
    }
    __syncthreads();
  }
  // bias + gelu pass: thread owns column tid
  {
    const float bias = b1[(size_t)te * kH + h0 + tid];
#pragma unroll
    for (int b = 0; b < kB; ++b) hid[b][tid] = gelu_exact(hid[b][tid] + bias);
  }
  __syncthreads();

  // ---- phase 2: lane owns d = 4*lane..+3; wave owns h-strip [h0+64*wave, +64) ----
  // fc2 loads: non-temporal dwordx4, 64 consecutive 1 KB rows per wave.
  float4 acc2[kB];
#pragma unroll
  for (int b = 0; b < kB; ++b) acc2[b] = make_float4(0.f, 0.f, 0.f, 0.f);
  {
    const float4* __restrict__ wp =
        reinterpret_cast<const float4*>(fc2 + (size_t)te * (kH * kD));  // [h][kD/4]
    const int hb = wave * 64;
    for (int hg = 0; hg < 16; ++hg) {
      const int hl = hb + hg * 4;
      const int h  = h0 + hl;
      const float4 wv0 = ntload4(wp + (size_t)(h + 0) * (kD / 4) + lane);
      const float4 wv1 = ntload4(wp + (size_t)(h + 1) * (kD / 4) + lane);
      const float4 wv2 = ntload4(wp + (size_t)(h + 2) * (kD / 4) + lane);
      const float4 wv3 = ntload4(wp + (size_t)(h + 3) * (kD / 4) + lane);
#pragma unroll
      for (int b = 0; b < kB; ++b) {
        const float4 hv = *reinterpret_cast<const float4*>(&hid[b][hl]);
        acc2[b].x = fmaf(hv.x, wv0.x, acc2[b].x);
        acc2[b].y = fmaf(hv.x, wv0.y, acc2[b].y);
        acc2[b].z = fmaf(hv.x, wv0.z, acc2[b].z);
        acc2[b].w = fmaf(hv.x, wv0.w, acc2[b].w);
        acc2[b].x = fmaf(hv.y, wv1.x, acc2[b].x);
        acc2[b].y = fmaf(hv.y, wv1.y, acc2[b].y);
        acc2[b].z = fmaf(hv.y, wv1.z, acc2[b].z);
        acc2[b].w = fmaf(hv.y, wv1.w, acc2[b].w);
        acc2[b].x = fmaf(hv.z, wv2.x, acc2[b].x);
        acc2[b].y = fmaf(hv.z, wv2.y, acc2[b].y);
        acc2[b].z = fmaf(hv.z, wv2.z, acc2[b].z);
        acc2[b].w = fmaf(hv.z, wv2.w, acc2[b].w);
        acc2[b].x = fmaf(hv.w, wv3.x, acc2[b].x);
        acc2[b].y = fmaf(hv.w, wv3.y, acc2[b].y);
        acc2[b].z = fmaf(hv.w, wv3.z, acc2[b].z);
        acc2[b].w = fmaf(hv.w, wv3.w, acc2[b].w);
      }
    }
  }
  // cross-wave combine into red by rotation
#pragma unroll
  for (int g = 0; g < 4; ++g) {
    if (wave == g) {
#pragma unroll
      for (int b = 0; b < kB; ++b) {
        float4* rp = reinterpret_cast<float4*>(&red[b][0]) + lane;
        if (g == 0) {
          *rp = acc2[b];
        } else {
          float4 v = *rp;
          v.x += acc2[b].x; v.y += acc2[b].y; v.z += acc2[b].z; v.w += acc2[b].w;
          *rp = v;
        }
      }
    }
    __syncthreads();
  }

  // ---- epilogue: thread owns d = tid; gate-scale and accumulate over e ----
  {
    const float b2v = (c == 0) ? b2[(size_t)te * kD + tid] : 0.f;
#pragma unroll
    for (int b = 0; b < kB; ++b)
      atomicAdd(&out[((size_t)b * kT + t) * kD + tid], gates_s[b] * (red[b][tid] + b2v));

    if (c == 0 && tid == 0) {
      float gs = 0.f;
#pragma unroll
      for (int b = 0; b < kB; ++b) gs += gates_s[b];
      atomicAdd(&out[(size_t)kB * kT * kD], 0.01f * gs * (1.0f / (kB * kT)));
    }
  }
}

}  // namespace

extern "C" void kernel_launch(void* const* d_in, const int* in_sizes, int n_in,
                              void* d_out, int out_size, void* d_ws, size_t ws_size,
                              hipStream_t stream) {
  const float* x   = (const float*)d_in[0];
  const float* fc1 = (const float*)d_in[1];
  const float* b1  = (const float*)d_in[2];
  const float* fc2 = (const float*)d_in[3];
  const float* b2  = (const float*)d_in[4];
  const float* Wr  = (const float*)d_in[5];
  const float* br  = (const float*)d_in[6];
  float* out = (float*)d_out;

  // Zero the accumulation target every call (graph replays must be
  // deterministic; harness does not re-poison between replays).
  (void)hipMemsetAsync(d_out, 0, (size_t)out_size * sizeof(float), stream);

  moe_ffn_kernel<<<dim3(kT * kE * kNC), dim3(256), 0, stream>>>(
      x, fc1, b1, fc2, b2, Wr, br, out);
}